// Round 7
// baseline (1206.521 us; speedup 1.0000x reference)
//
#include <hip/hip_runtime.h>
#include <math.h>

typedef _Float16 f16;
typedef _Float16 f16x2 __attribute__((ext_vector_type(2)));
typedef _Float16 f16x8 __attribute__((ext_vector_type(8)));
typedef float f32x4 __attribute__((ext_vector_type(4)));

#define NB 16
#define SS 2048
#define DD 512

// async global->LDS, 16B per lane; LDS dst = wave-uniform base + lane*16B
__device__ __forceinline__ void gl_lds16(const void* g, void* l) {
  __builtin_amdgcn_global_load_lds(
      (const __attribute__((address_space(1))) unsigned int*)g,
      (__attribute__((address_space(3))) unsigned int*)l, 16, 0, 0);
}

// pack two f32 -> f16x2 word
__device__ __forceinline__ int pk2(float a, float b) {
  f16x2 t = {(f16)a, (f16)b};
  return __builtin_bit_cast(int, t);
}

// ---------------- cast x (fp32) -> fp16, 8 elems/thread ----------------
__global__ __launch_bounds__(256) void cast_kernel(const float* __restrict__ x,
                                                   f16* __restrict__ o) {
  size_t i = (size_t)blockIdx.x * 256 + threadIdx.x;
  const float4* p = (const float4*)x + i * 2;
  float4 a = p[0], b = p[1];
  f16x8 v = {(f16)a.x, (f16)a.y, (f16)a.z, (f16)a.w,
             (f16)b.x, (f16)b.y, (f16)b.z, (f16)b.w};
  *((f16x8*)o + i) = v;
}

// ---------------- transpose 512x512 weights, fp32 -> fp16, z picks matrix ----
__global__ __launch_bounds__(256) void transpose_kernel(
    const float* __restrict__ W0, const float* __restrict__ W1,
    const float* __restrict__ W2, f16* __restrict__ T0, f16* __restrict__ T1,
    f16* __restrict__ T2) {
  const float* W = (blockIdx.z == 0) ? W0 : (blockIdx.z == 1) ? W1 : W2;
  f16* Wt = (blockIdx.z == 0) ? T0 : (blockIdx.z == 1) ? T1 : T2;
  __shared__ float t[32][33];
  int bx = blockIdx.x * 32, by = blockIdx.y * 32;
  int c = threadIdx.x & 31, r0 = threadIdx.x >> 5;
  for (int r = r0; r < 32; r += 8) t[r][c] = W[(size_t)(by + r) * DD + bx + c];
  __syncthreads();
  for (int r = r0; r < 32; r += 8) Wt[(size_t)(bx + r) * DD + by + c] = (f16)t[c][r];
}

// ---------------- fused QKV GEMM, R10 (kept: proven -50us) ----------------
__global__ __launch_bounds__(512, 2) void gemmQKV_kernel(
    const f16* __restrict__ xh, const f16* __restrict__ WqT,
    const f16* __restrict__ WkT, const f16* __restrict__ WvT,
    f16* __restrict__ Qh, f16* __restrict__ Kh, f16* __restrict__ Vth,
    const float* __restrict__ bq, const float* __restrict__ bk,
    const float* __restrict__ bv) {
  const int wid = (blockIdx.x & 7) * 96 + (blockIdx.x >> 3);  // bijective XCD swz
  const f16* Wm;
  f16* C;
  const float* bias;
  size_t x0;
  size_t crow0, ccol0;
  int w0, ldc, bias_row;
  float scale;
  bool isV;
  if (wid < 512) {  // Q (0..255) / K (256..511): C[32768][512] = xh * W^T
    const bool isK = wid >= 256;
    const int r = wid & 255;
    x0 = (size_t)(r >> 1) * 256;
    w0 = (r & 1) * 256;
    Wm = isK ? WkT : WqT;
    C = isK ? Kh : Qh;
    bias = isK ? bk : bq;
    crow0 = x0;
    ccol0 = (size_t)w0;
    ldc = DD;
    bias_row = 0;
    scale = isK ? 1.0f : 0.125f;
    isV = false;
  } else {  // V^T per batch: Vt[512][2048] = WvT * x_b^T (operand-swap)
    const int v = wid - 512;
    const int b = v >> 4, e = (v >> 3) & 1, s = v & 7;
    x0 = (size_t)b * SS + (size_t)s * 256;
    w0 = e * 256;
    Wm = WvT;
    C = Vth + (size_t)b * DD * SS;
    bias = bv;
    crow0 = (size_t)w0;
    ccol0 = (size_t)s * 256;
    ldc = SS;
    bias_row = 1;
    scale = 1.0f;
    isV = true;
  }
  __shared__ f16 Xsh[2][256][64];
  __shared__ f16 Wsh[2][256][64];
  const int tid = threadIdx.x, lane = tid & 63, wave = tid >> 6;
  const int wm2 = wave >> 2, wn2 = wave & 3;
  const int l15 = lane & 15, lq = lane >> 4;
  const int srow = lane >> 3;
  const int sseg = (lane & 7) ^ srow;
  f32x4 acc[8][4] = {};
  auto stage = [&](int sb, int kt) {
#pragma unroll
    for (int g = 0; g < 4; ++g) {
      const int r0 = wave * 32 + g * 8;
      gl_lds16(xh + (x0 + r0 + srow) * DD + kt * 64 + sseg * 8,
               (f16*)&Xsh[sb][r0][0] + lane * 8);
      gl_lds16(Wm + (size_t)(w0 + r0 + srow) * DD + kt * 64 + sseg * 8,
               (f16*)&Wsh[sb][r0][0] + lane * 8);
    }
  };
  stage(0, 0);
  asm volatile("s_waitcnt vmcnt(0)" ::: "memory");
  asm volatile("s_barrier" ::: "memory");
  for (int kt = 0; kt < 8; ++kt) {
    const int buf = kt & 1;
    if (kt < 7) stage(buf ^ 1, kt + 1);
    const f16(*As)[64] = isV ? Wsh[buf] : Xsh[buf];
    const f16(*Bs)[64] = isV ? Xsh[buf] : Wsh[buf];
#pragma unroll
    for (int ks = 0; ks < 2; ++ks) {
      const int seg = ((ks * 4 + lq) ^ (l15 & 7)) * 8;
      f16x8 bf[4];
#pragma unroll
      for (int j = 0; j < 4; ++j)
        bf[j] = *(const f16x8*)&Bs[64 * wn2 + 16 * j + l15][seg];
#pragma unroll
      for (int mh = 0; mh < 2; ++mh) {
        f16x8 af[4];
#pragma unroll
        for (int i = 0; i < 4; ++i)
          af[i] = *(const f16x8*)&As[128 * wm2 + 64 * mh + 16 * i + l15][seg];
        __builtin_amdgcn_s_setprio(1);
#pragma unroll
        for (int i = 0; i < 4; ++i)
#pragma unroll
          for (int j = 0; j < 4; ++j)
            acc[4 * mh + i][j] = __builtin_amdgcn_mfma_f32_16x16x32_f16(
                af[i], bf[j], acc[4 * mh + i][j], 0, 0, 0);
        __builtin_amdgcn_s_setprio(0);
        if (ks == 1 && mh == 1)
          asm volatile("s_waitcnt vmcnt(0)" ::: "memory");
        asm volatile("s_barrier" ::: "memory");
      }
    }
  }
#pragma unroll
  for (int i = 0; i < 8; ++i) {
    const int arow = 128 * wm2 + 16 * i + 4 * lq;
#pragma unroll
    for (int j = 0; j < 4; ++j) {
      const int acol = 64 * wn2 + 16 * j + l15;
#pragma unroll
      for (int r = 0; r < 4; ++r) {
        const size_t rr = crow0 + arow + r;
        const size_t cc = ccol0 + acol;
        const float bvv = bias_row ? bias[rr] : bias[cc];
        C[rr * ldc + cc] = (f16)((acc[i][j][r] + bvv) * scale);
      }
    }
  }
}

// ---------------- flash attention, R11: 32 q-rows/wave @ 1 wave/SIMD ---------
// R10 audit: attn is ~97% LDS-pipe busy; the invariant is LDS bytes/iter =
// (K+V tile) x n_waves with q-coverage 16 x n_waves (Q+O register walls at
// 256 VGPR). R11 breaks the wall with the 512-VGPR single-wave-per-SIMD mode
// (launch_bounds(256,1); m08/m24: no spill through ~450):
//   - 4 waves x 32 q-rows each (qf 128 + acco 256 + state ~60 = ~448 VGPR)
//   - K/V tile read by 4 waves, not 8 -> LDS traffic HALVES
//   - per K-frag pair: 4 QK MFMAs (2 q-halves); per V-frag: 2 PV MFMAs
//   - softmax/butterfly/defer-max machinery duplicated per q-half (wave-local,
//     R6-proven); no new barriers
// ILP covers the lost TLP: 64 indep ds_reads + 130 MFMAs per iter per wave;
// DMA drained only at end-of-iter __syncthreads (~3k cyc after issue).
__global__ __launch_bounds__(256, 1) void attn_kernel(
    const f16* __restrict__ Q, const f16* __restrict__ K,
    const f16* __restrict__ Vt, float* __restrict__ out) {
  const int id = blockIdx.x;
  const int b = (id & 7) + ((id >> 7) << 3);  // XCD x gets batches {x, x+8}
  const int qt = (id >> 3) & 15;
  const int tid = threadIdx.x, lane = tid & 63, wave = tid >> 6;
  const int l15 = lane & 15, lq = lane >> 4;

  __shared__ __align__(16) f16 Kl[2][32][520];  // [key][d], 1040B rows
  __shared__ __align__(16) f16 Vl[2][512][32];  // [e][key], XOR-swizzled quarters

  // persistent Q fragments: wave owns q-rows 32*wave .. 32*wave+31
  const f16* qp0 = Q + ((size_t)(b * SS + qt * 128 + wave * 32 + l15)) * DD + lq * 8;
  f16x8 qf0[16], qf1[16];
#pragma unroll
  for (int kk = 0; kk < 16; ++kk) qf0[kk] = *(const f16x8*)(qp0 + kk * 32);
#pragma unroll
  for (int kk = 0; kk < 16; ++kk) qf1[kk] = *(const f16x8*)(qp0 + 16 * DD + kk * 32);

  const f16* Kb = K + (size_t)b * SS * DD;   // [key][d]
  const f16* Vb = Vt + (size_t)b * DD * SS;  // [e][s]

  const int sdata = (lane & 3) ^ ((lane >> 3) & 3);
  const int vrow = lane >> 2;
  const int vs_off = (lq ^ ((l15 >> 1) & 3)) * 8;

  f16x8 onef;
#pragma unroll
  for (int j = 0; j < 8; ++j) onef[j] = (f16)1.0f;

  auto stage = [&](int sb, int kb) {
#pragma unroll
    for (int rr = 0; rr < 8; ++rr) {  // K: 32 rows over 4 waves
      int row = wave * 8 + rr;
      gl_lds16(Kb + ((size_t)(kb + row)) * DD + lane * 8, &Kl[sb][row][lane * 8]);
    }
#pragma unroll
    for (int i = 0; i < 8; ++i) {  // V: 512 e-rows over 4 waves, 16/instr
      int e0 = wave * 128 + i * 16;
      gl_lds16(Vb + (size_t)(e0 + vrow) * SS + kb + sdata * 8,
               (f16*)&Vl[sb][e0][0] + lane * 8);
    }
  };

  stage(0, 0);
  __syncthreads();

  f32x4 acco0[32] = {}, acco1[32] = {};
  f32x4 accl0 = {}, accl1 = {};
  float m0 = -1e30f, m1 = -1e30f;

  for (int it = 0; it < 64; ++it) {
    const int buf = it & 1;
    if (it < 63) stage(buf ^ 1, (it + 1) * 32);
    // ---- QK^T (swapped): 2 key-halves x 2 q-halves; K-frags shared ----
    f32x4 s00 = {}, s01 = {}, s10 = {}, s11 = {};
#pragma unroll
    for (int kk = 0; kk < 16; ++kk) {
      f16x8 b0 = *(const f16x8*)&Kl[buf][l15][kk * 32 + lq * 8];
      f16x8 b1 = *(const f16x8*)&Kl[buf][16 + l15][kk * 32 + lq * 8];
      s00 = __builtin_amdgcn_mfma_f32_16x16x32_f16(b0, qf0[kk], s00, 0, 0, 0);
      s01 = __builtin_amdgcn_mfma_f32_16x16x32_f16(b1, qf0[kk], s01, 0, 0, 0);
      s10 = __builtin_amdgcn_mfma_f32_16x16x32_f16(b0, qf1[kk], s10, 0, 0, 0);
      s11 = __builtin_amdgcn_mfma_f32_16x16x32_f16(b1, qf1[kk], s11, 0, 0, 0);
    }
    // ---- softmax per q-half (R6 machinery x2) ----
    f16x8 pa0, pa1;
#pragma unroll
    for (int h = 0; h < 2; ++h) {
      f32x4 sa0 = h ? s10 : s00;
      f32x4 sa1 = h ? s11 : s01;
      float& m = h ? m1 : m0;
      f32x4& accl = h ? accl1 : accl0;
      f32x4* acco = h ? acco1 : acco0;
      float lm = fmaxf(fmaxf(fmaxf(sa0[0], sa0[1]), fmaxf(sa0[2], sa0[3])),
                       fmaxf(fmaxf(sa1[0], sa1[1]), fmaxf(sa1[2], sa1[3])));
      if (__any(lm > m + 8.0f)) {
        float mx = fmaxf(lm, __shfl_xor(lm, 16));
        mx = fmaxf(mx, __shfl_xor(mx, 32));
        float mn = fmaxf(m, mx);
        float al = __expf(m - mn);
        m = mn;
        float alr[4];
#pragma unroll
        for (int r = 0; r < 4; ++r) alr[r] = __shfl(al, 4 * lq + r);
#pragma unroll
        for (int t = 0; t < 32; ++t)
#pragma unroll
          for (int r = 0; r < 4; ++r) acco[t][r] *= alr[r];
#pragma unroll
        for (int r = 0; r < 4; ++r) accl[r] *= alr[r];
      }
      int A0 = pk2(__expf(sa0[0] - m), __expf(sa0[1] - m));
      int A1 = pk2(__expf(sa0[2] - m), __expf(sa0[3] - m));
      int B0 = pk2(__expf(sa1[0] - m), __expf(sa1[1] - m));
      int B1 = pk2(__expf(sa1[2] - m), __expf(sa1[3] - m));
      const bool low = (lq < 2);
      int t0s = low ? B0 : A0, t1s = low ? B1 : A1;
      int X0 = __shfl_xor(t0s, 32), X1 = __shfl_xor(t1s, 32);
      int Y0 = low ? A0 : B0, Y1 = low ? A1 : B1;
      const bool sx = (lq == 0) || (lq == 3);
      int u0 = sx ? X0 : Y0, u1 = sx ? X1 : Y1;
      int Z0 = __shfl_xor(u0, 16), Z1 = __shfl_xor(u1, 16);
      union PU { int i[4]; f16x8 v; } pu;
      pu.i[0] = (lq == 0) ? Y0 : ((lq == 2) ? X0 : Z0);
      pu.i[1] = (lq == 0) ? Y1 : ((lq == 2) ? X1 : Z1);
      pu.i[2] = (lq == 1) ? X0 : ((lq == 3) ? Y0 : Z0);
      pu.i[3] = (lq == 1) ? X1 : ((lq == 3) ? Y1 : Z1);
      f16x8 pa = pu.v;
      accl = __builtin_amdgcn_mfma_f32_16x16x32_f16(pa, onef, accl, 0, 0, 0);
      if (h) pa1 = pa; else pa0 = pa;
    }
    // ---- PV: V-frag read once, feeds both q-halves ----
#pragma unroll
    for (int nn = 0; nn < 32; ++nn) {
      f16x8 vf = *(const f16x8*)&Vl[buf][nn * 16 + l15][vs_off];
      acco0[nn] = __builtin_amdgcn_mfma_f32_16x16x32_f16(pa0, vf, acco0[nn], 0, 0, 0);
      acco1[nn] = __builtin_amdgcn_mfma_f32_16x16x32_f16(pa1, vf, acco1[nn], 0, 0, 0);
    }
    __syncthreads();  // drains DMA into buf^1; protects buf from overwrite
  }
  // ---- epilogue ----
  float inv0[4], inv1[4];
#pragma unroll
  for (int r = 0; r < 4; ++r) inv0[r] = 1.0f / accl0[r];
#pragma unroll
  for (int r = 0; r < 4; ++r) inv1[r] = 1.0f / accl1[r];
  const size_t ob = ((size_t)(b * SS + qt * 128 + wave * 32 + 4 * lq)) * DD + l15;
#pragma unroll
  for (int nn = 0; nn < 32; ++nn)
#pragma unroll
    for (int r = 0; r < 4; ++r) {
      out[ob + (size_t)r * DD + nn * 16] = acco0[nn][r] * inv0[r];
      out[ob + (size_t)(16 + r) * DD + nn * 16] = acco1[nn][r] * inv1[r];
    }
}

extern "C" void kernel_launch(void* const* d_in, const int* in_sizes, int n_in,
                              void* d_out, int out_size, void* d_ws, size_t ws_size,
                              hipStream_t stream) {
  const float* x = (const float*)d_in[0];
  const float* Wq = (const float*)d_in[1];
  const float* bq = (const float*)d_in[2];
  const float* Wk = (const float*)d_in[3];
  const float* bk = (const float*)d_in[4];
  const float* Wv = (const float*)d_in[5];
  const float* bv = (const float*)d_in[6];
  float* out = (float*)d_out;
  f16* ws = (f16*)d_ws;
  const size_t NX = (size_t)NB * SS * DD;  // 16,777,216
  f16* xh = ws;
  f16* Qh = ws + NX;
  f16* Kh = ws + 2 * NX;
  f16* Vth = ws + 3 * NX;
  f16* WqT = ws + 4 * NX;
  f16* WkT = WqT + DD * DD;
  f16* WvT = WkT + DD * DD;

  cast_kernel<<<NX / 8 / 256, 256, 0, stream>>>(x, xh);
  transpose_kernel<<<dim3(16, 16, 3), 256, 0, stream>>>(Wq, Wk, Wv, WqT, WkT, WvT);
  gemmQKV_kernel<<<768, 512, 0, stream>>>(xh, WqT, WkT, WvT, Qh, Kh, Vth, bq, bk, bv);
  attn_kernel<<<256, 256, 0, stream>>>(Qh, Kh, Vth, out);
}

// Round 8
// 368.815 us; speedup vs baseline: 3.2713x; 3.2713x over previous
//
#include <hip/hip_runtime.h>
#include <math.h>

typedef _Float16 f16;
typedef _Float16 f16x2 __attribute__((ext_vector_type(2)));
typedef _Float16 f16x8 __attribute__((ext_vector_type(8)));
typedef float f32x4 __attribute__((ext_vector_type(4)));

#define NB 16
#define SS 2048
#define DD 512

// async global->LDS, 16B per lane; LDS dst = wave-uniform base + lane*16B
__device__ __forceinline__ void gl_lds16(const void* g, void* l) {
  __builtin_amdgcn_global_load_lds(
      (const __attribute__((address_space(1))) unsigned int*)g,
      (__attribute__((address_space(3))) unsigned int*)l, 16, 0, 0);
}

// pack two f32 -> f16x2 word
__device__ __forceinline__ int pk2(float a, float b) {
  f16x2 t = {(f16)a, (f16)b};
  return __builtin_bit_cast(int, t);
}

// ---------------- cast x (fp32) -> fp16, 8 elems/thread ----------------
__global__ __launch_bounds__(256) void cast_kernel(const float* __restrict__ x,
                                                   f16* __restrict__ o) {
  size_t i = (size_t)blockIdx.x * 256 + threadIdx.x;
  const float4* p = (const float4*)x + i * 2;
  float4 a = p[0], b = p[1];
  f16x8 v = {(f16)a.x, (f16)a.y, (f16)a.z, (f16)a.w,
             (f16)b.x, (f16)b.y, (f16)b.z, (f16)b.w};
  *((f16x8*)o + i) = v;
}

// ---------------- transpose 512x512 weights, fp32 -> fp16, z picks matrix ----
__global__ __launch_bounds__(256) void transpose_kernel(
    const float* __restrict__ W0, const float* __restrict__ W1,
    const float* __restrict__ W2, f16* __restrict__ T0, f16* __restrict__ T1,
    f16* __restrict__ T2) {
  const float* W = (blockIdx.z == 0) ? W0 : (blockIdx.z == 1) ? W1 : W2;
  f16* Wt = (blockIdx.z == 0) ? T0 : (blockIdx.z == 1) ? T1 : T2;
  __shared__ float t[32][33];
  int bx = blockIdx.x * 32, by = blockIdx.y * 32;
  int c = threadIdx.x & 31, r0 = threadIdx.x >> 5;
  for (int r = r0; r < 32; r += 8) t[r][c] = W[(size_t)(by + r) * DD + bx + c];
  __syncthreads();
  for (int r = r0; r < 32; r += 8) Wt[(size_t)(bx + r) * DD + by + c] = (f16)t[c][r];
}

// ---------------- fused QKV GEMM, R10 (proven: non-attn 215->161us) ----------
// 256x256 tile, BK=64, 4-phase counted-vmcnt schedule: full next-tile prefetch
// issued at phase 0, vmcnt(0) drain deferred to end of phase 3 (4 phases of
// latency cover), raw s_barrier per phase, T5 setprio around MFMA clusters.
// Both-sides XOR swizzle on [256][64] tiles (128B rows).
__global__ __launch_bounds__(512, 2) void gemmQKV_kernel(
    const f16* __restrict__ xh, const f16* __restrict__ WqT,
    const f16* __restrict__ WkT, const f16* __restrict__ WvT,
    f16* __restrict__ Qh, f16* __restrict__ Kh, f16* __restrict__ Vth,
    const float* __restrict__ bq, const float* __restrict__ bk,
    const float* __restrict__ bv) {
  const int wid = (blockIdx.x & 7) * 96 + (blockIdx.x >> 3);  // bijective XCD swz
  const f16* Wm;
  f16* C;
  const float* bias;
  size_t x0;
  size_t crow0, ccol0;
  int w0, ldc, bias_row;
  float scale;
  bool isV;
  if (wid < 512) {  // Q (0..255) / K (256..511): C[32768][512] = xh * W^T
    const bool isK = wid >= 256;
    const int r = wid & 255;
    x0 = (size_t)(r >> 1) * 256;
    w0 = (r & 1) * 256;
    Wm = isK ? WkT : WqT;
    C = isK ? Kh : Qh;
    bias = isK ? bk : bq;
    crow0 = x0;
    ccol0 = (size_t)w0;
    ldc = DD;
    bias_row = 0;
    scale = isK ? 1.0f : 0.125f;  // fold 1/sqrt(64) into Q
    isV = false;
  } else {  // V^T per batch: Vt[512][2048] = WvT * x_b^T (operand-swap)
    const int v = wid - 512;
    const int b = v >> 4, e = (v >> 3) & 1, s = v & 7;
    x0 = (size_t)b * SS + (size_t)s * 256;
    w0 = e * 256;
    Wm = WvT;
    C = Vth + (size_t)b * DD * SS;
    bias = bv;
    crow0 = (size_t)w0;
    ccol0 = (size_t)s * 256;
    ldc = SS;
    bias_row = 1;
    scale = 1.0f;
    isV = true;
  }
  __shared__ f16 Xsh[2][256][64];
  __shared__ f16 Wsh[2][256][64];
  const int tid = threadIdx.x, lane = tid & 63, wave = tid >> 6;
  const int wm2 = wave >> 2, wn2 = wave & 3;
  const int l15 = lane & 15, lq = lane >> 4;
  const int srow = lane >> 3;
  const int sseg = (lane & 7) ^ srow;
  f32x4 acc[8][4] = {};
  auto stage = [&](int sb, int kt) {
#pragma unroll
    for (int g = 0; g < 4; ++g) {
      const int r0 = wave * 32 + g * 8;
      gl_lds16(xh + (x0 + r0 + srow) * DD + kt * 64 + sseg * 8,
               (f16*)&Xsh[sb][r0][0] + lane * 8);
      gl_lds16(Wm + (size_t)(w0 + r0 + srow) * DD + kt * 64 + sseg * 8,
               (f16*)&Wsh[sb][r0][0] + lane * 8);
    }
  };
  stage(0, 0);
  asm volatile("s_waitcnt vmcnt(0)" ::: "memory");
  asm volatile("s_barrier" ::: "memory");
  for (int kt = 0; kt < 8; ++kt) {
    const int buf = kt & 1;
    if (kt < 7) stage(buf ^ 1, kt + 1);
    const f16(*As)[64] = isV ? Wsh[buf] : Xsh[buf];
    const f16(*Bs)[64] = isV ? Xsh[buf] : Wsh[buf];
#pragma unroll
    for (int ks = 0; ks < 2; ++ks) {
      const int seg = ((ks * 4 + lq) ^ (l15 & 7)) * 8;
      f16x8 bf[4];
#pragma unroll
      for (int j = 0; j < 4; ++j)
        bf[j] = *(const f16x8*)&Bs[64 * wn2 + 16 * j + l15][seg];
#pragma unroll
      for (int mh = 0; mh < 2; ++mh) {
        f16x8 af[4];
#pragma unroll
        for (int i = 0; i < 4; ++i)
          af[i] = *(const f16x8*)&As[128 * wm2 + 64 * mh + 16 * i + l15][seg];
        __builtin_amdgcn_s_setprio(1);
#pragma unroll
        for (int i = 0; i < 4; ++i)
#pragma unroll
          for (int j = 0; j < 4; ++j)
            acc[4 * mh + i][j] = __builtin_amdgcn_mfma_f32_16x16x32_f16(
                af[i], bf[j], acc[4 * mh + i][j], 0, 0, 0);
        __builtin_amdgcn_s_setprio(0);
        if (ks == 1 && mh == 1)
          asm volatile("s_waitcnt vmcnt(0)" ::: "memory");
        asm volatile("s_barrier" ::: "memory");
      }
    }
  }
#pragma unroll
  for (int i = 0; i < 8; ++i) {
    const int arow = 128 * wm2 + 16 * i + 4 * lq;
#pragma unroll
    for (int j = 0; j < 4; ++j) {
      const int acol = 64 * wn2 + 16 * j + l15;
#pragma unroll
      for (int r = 0; r < 4; ++r) {
        const size_t rr = crow0 + arow + r;
        const size_t cc = ccol0 + acol;
        const float bvv = bias_row ? bias[rr] : bias[cc];
        C[rr * ldc + cc] = (f16)((acc[i][j][r] + bvv) * scale);
      }
    }
  }
}

// ---------------- flash attention, R6 (proven floor: ~200us) ----------------
// Swapped-QK, P fully in-register, wave-independent softmax, ONE barrier/iter.
// DO NOT revisit (measured refutations):
//  - R9 D-partitioned PV (cross-wave P via LDS): mid-iter block barrier
//    serialized wave phases -> 215us (worse).
//  - R11 32-q-rows/wave @ launch_bounds(256,1): arch VGPR cap is 256/wave
//    regardless of unified-file budget; acco spilled -> 1.6GB scratch traffic,
//    1048us (5x worse).
//  - SQ_LDS_BANK_CONFLICT = 2^24 exactly = 2/b128-read = the free 2-way
//    aliasing artifact (m136); K/V read mappings already hit the 8-clk b128
//    floor. Kernel sits at the ~85B/cyc ds_read_b128 issue ceiling (m134).
__global__ __launch_bounds__(512, 2) void attn_kernel(
    const f16* __restrict__ Q, const f16* __restrict__ K,
    const f16* __restrict__ Vt, float* __restrict__ out) {
  const int id = blockIdx.x;
  const int b = (id & 7) + ((id >> 7) << 3);  // XCD x gets batches {x, x+8}
  const int qt = (id >> 3) & 15;
  const int tid = threadIdx.x, lane = tid & 63, wave = tid >> 6;
  const int l15 = lane & 15, lq = lane >> 4;

  __shared__ __align__(16) f16 Kl[2][32][520];  // [key][d], 1040B rows
  __shared__ __align__(16) f16 Vl[2][512][32];  // [e][key], XOR-swizzled quarters

  const f16* qp = Q + ((size_t)(b * SS + qt * 128 + wave * 16 + l15)) * DD + lq * 8;
  f16x8 qf[16];
#pragma unroll
  for (int kk = 0; kk < 16; ++kk) qf[kk] = *(const f16x8*)(qp + kk * 32);

  const f16* Kb = K + (size_t)b * SS * DD;   // [key][d]
  const f16* Vb = Vt + (size_t)b * DD * SS;  // [e][s]

  const int sdata = (lane & 3) ^ ((lane >> 3) & 3);
  const int vrow = lane >> 2;
  const int vs_off = (lq ^ ((l15 >> 1) & 3)) * 8;

  f16x8 onef;
#pragma unroll
  for (int j = 0; j < 8; ++j) onef[j] = (f16)1.0f;

  auto stage = [&](int sb, int kb) {
#pragma unroll
    for (int rr = 0; rr < 4; ++rr) {
      int row = wave * 4 + rr;
      gl_lds16(Kb + ((size_t)(kb + row)) * DD + lane * 8, &Kl[sb][row][lane * 8]);
    }
#pragma unroll
    for (int i = 0; i < 4; ++i) {
      int e0 = wave * 64 + i * 16;
      gl_lds16(Vb + (size_t)(e0 + vrow) * SS + kb + sdata * 8,
               (f16*)&Vl[sb][e0][0] + lane * 8);
    }
  };

  stage(0, 0);
  __syncthreads();

  f32x4 acco[32] = {};
  f32x4 accl = {};
  float m = -1e30f;

  for (int it = 0; it < 64; ++it) {
    const int buf = it & 1;
    if (it < 63) stage(buf ^ 1, (it + 1) * 32);
    f32x4 sa0 = {}, sa1 = {};
#pragma unroll
    for (int kk = 0; kk < 16; ++kk) {
      f16x8 b0 = *(const f16x8*)&Kl[buf][l15][kk * 32 + lq * 8];
      f16x8 b1 = *(const f16x8*)&Kl[buf][16 + l15][kk * 32 + lq * 8];
      sa0 = __builtin_amdgcn_mfma_f32_16x16x32_f16(b0, qf[kk], sa0, 0, 0, 0);
      sa1 = __builtin_amdgcn_mfma_f32_16x16x32_f16(b1, qf[kk], sa1, 0, 0, 0);
    }
    float lm = fmaxf(fmaxf(fmaxf(sa0[0], sa0[1]), fmaxf(sa0[2], sa0[3])),
                     fmaxf(fmaxf(sa1[0], sa1[1]), fmaxf(sa1[2], sa1[3])));
    if (__any(lm > m + 8.0f)) {
      float mx = lm;
      mx = fmaxf(mx, __shfl_xor(mx, 16));
      mx = fmaxf(mx, __shfl_xor(mx, 32));
      float mn = fmaxf(m, mx);
      float al = __expf(m - mn);
      m = mn;
      float alr[4];
#pragma unroll
      for (int r = 0; r < 4; ++r) alr[r] = __shfl(al, 4 * lq + r);
#pragma unroll
      for (int t = 0; t < 32; ++t)
#pragma unroll
        for (int r = 0; r < 4; ++r) acco[t][r] *= alr[r];
#pragma unroll
      for (int r = 0; r < 4; ++r) accl[r] *= alr[r];
    }
    int A0 = pk2(__expf(sa0[0] - m), __expf(sa0[1] - m));
    int A1 = pk2(__expf(sa0[2] - m), __expf(sa0[3] - m));
    int B0 = pk2(__expf(sa1[0] - m), __expf(sa1[1] - m));
    int B1 = pk2(__expf(sa1[2] - m), __expf(sa1[3] - m));
    const bool low = (lq < 2);
    int s0 = low ? B0 : A0, s1 = low ? B1 : A1;
    int X0 = __shfl_xor(s0, 32), X1 = __shfl_xor(s1, 32);
    int Y0 = low ? A0 : B0, Y1 = low ? A1 : B1;
    const bool sx = (lq == 0) || (lq == 3);
    int t0 = sx ? X0 : Y0, t1 = sx ? X1 : Y1;
    int Z0 = __shfl_xor(t0, 16), Z1 = __shfl_xor(t1, 16);
    union PU { int i[4]; f16x8 v; } pu;
    pu.i[0] = (lq == 0) ? Y0 : ((lq == 2) ? X0 : Z0);
    pu.i[1] = (lq == 0) ? Y1 : ((lq == 2) ? X1 : Z1);
    pu.i[2] = (lq == 1) ? X0 : ((lq == 3) ? Y0 : Z0);
    pu.i[3] = (lq == 1) ? X1 : ((lq == 3) ? Y1 : Z1);
    f16x8 pa = pu.v;
    accl = __builtin_amdgcn_mfma_f32_16x16x32_f16(pa, onef, accl, 0, 0, 0);
#pragma unroll
    for (int nn = 0; nn < 32; ++nn) {
      f16x8 vf = *(const f16x8*)&Vl[buf][nn * 16 + l15][vs_off];
      acco[nn] = __builtin_amdgcn_mfma_f32_16x16x32_f16(pa, vf, acco[nn], 0, 0, 0);
    }
    __syncthreads();
  }
  float inv[4];
#pragma unroll
  for (int r = 0; r < 4; ++r) inv[r] = 1.0f / accl[r];
  const size_t ob = ((size_t)(b * SS + qt * 128 + wave * 16 + 4 * lq)) * DD + l15;
#pragma unroll
  for (int nn = 0; nn < 32; ++nn)
#pragma unroll
    for (int r = 0; r < 4; ++r)
      out[ob + (size_t)r * DD + nn * 16] = acco[nn][r] * inv[r];
}

extern "C" void kernel_launch(void* const* d_in, const int* in_sizes, int n_in,
                              void* d_out, int out_size, void* d_ws, size_t ws_size,
                              hipStream_t stream) {
  const float* x = (const float*)d_in[0];
  const float* Wq = (const float*)d_in[1];
  const float* bq = (const float*)d_in[2];
  const float* Wk = (const float*)d_in[3];
  const float* bk = (const float*)d_in[4];
  const float* Wv = (const float*)d_in[5];
  const float* bv = (const float*)d_in[6];
  float* out = (float*)d_out;
  f16* ws = (f16*)d_ws;
  const size_t NX = (size_t)NB * SS * DD;  // 16,777,216
  f16* xh = ws;
  f16* Qh = ws + NX;
  f16* Kh = ws + 2 * NX;
  f16* Vth = ws + 3 * NX;
  f16* WqT = ws + 4 * NX;
  f16* WkT = WqT + DD * DD;
  f16* WvT = WkT + DD * DD;

  cast_kernel<<<NX / 8 / 256, 256, 0, stream>>>(x, xh);
  transpose_kernel<<<dim3(16, 16, 3), 256, 0, stream>>>(Wq, Wk, Wv, WqT, WkT, WvT);
  gemmQKV_kernel<<<768, 512, 0, stream>>>(xh, WqT, WkT, WvT, Qh, Kh, Vth, bq, bk, bv);
  attn_kernel<<<256, 512, 0, stream>>>(Qh, Kh, Vth, out);
}